// Round 1
// baseline (2937.403 us; speedup 1.0000x reference)
//
#include <hip/hip_runtime.h>

// ---------------------------------------------------------------------------
// 2-layer GCN: per layer  h = X @ W^T ;  out[d] = b + sum_{e:dst=d} h[src]*norm
// norm = dinv[src]*dinv[dst], dinv = rsqrt(degree incl. self loop).
// Self-loop message (h[i]*dinv[i]^2) and bias are fused into the init kernel
// so the edge kernel only handles the 1.6M real edges with f32 atomics.
// ---------------------------------------------------------------------------

#define D 64

// --- degree count: one atomic per edge on dst ------------------------------
__global__ __launch_bounds__(256) void deg_kernel(const int* __restrict__ dst,
                                                  float* __restrict__ deg, int nE) {
    int e = blockIdx.x * 256 + threadIdx.x;
    if (e < nE) unsafeAtomicAdd(&deg[dst[e]], 1.0f);
}

// --- dinv = rsqrt(deg + 1)  (self loop adds 1; always > 0) -----------------
__global__ __launch_bounds__(256) void dinv_kernel(float* __restrict__ degdinv, int N) {
    int i = blockIdx.x * 256 + threadIdx.x;
    if (i < N) degdinv[i] = rsqrtf(degdinv[i] + 1.0f);
}

// --- H = X @ W^T : 64x64 block tile, 4x4 register tile ---------------------
// LDS holds x^T and W^T with row stride 68 floats (16B aligned rows; float4
// k-loop reads land as ds_read_b128 with <=2-way bank aliasing, which is free).
__global__ __launch_bounds__(256) void gemm_xwt(const float* __restrict__ X,
                                                const float* __restrict__ W,
                                                float* __restrict__ H, int N) {
    __shared__ float xt[64 * 68];
    __shared__ float wt[64 * 68];
    const int t = threadIdx.x;
    const int i0 = blockIdx.x * 64;

    // stage W^T: wt[k][j] = W[j*64 + k]   (coalesced global reads)
#pragma unroll
    for (int r = 0; r < 16; ++r) {
        int idx = r * 256 + t;
        int j = idx >> 6, k = idx & 63;
        wt[k * 68 + j] = W[idx];
    }
    // stage x^T: xt[k][i] = X[(i0+i)*64 + k]
#pragma unroll
    for (int r = 0; r < 16; ++r) {
        int idx = r * 256 + t;
        int i = idx >> 6, k = idx & 63;
        float v = 0.0f;
        if (i0 + i < N) v = X[(size_t)(i0 + i) * D + k];
        xt[k * 68 + i] = v;
    }
    __syncthreads();

    const int tn = (t & 15) * 4;   // node sub-tile
    const int tc = (t >> 4) * 4;   // col  sub-tile
    float acc[4][4] = {};
#pragma unroll 8
    for (int k = 0; k < 64; ++k) {
        const float4 xa = *(const float4*)(xt + k * 68 + tn);
        const float4 wb = *(const float4*)(wt + k * 68 + tc);
        acc[0][0] += xa.x * wb.x; acc[0][1] += xa.x * wb.y; acc[0][2] += xa.x * wb.z; acc[0][3] += xa.x * wb.w;
        acc[1][0] += xa.y * wb.x; acc[1][1] += xa.y * wb.y; acc[1][2] += xa.y * wb.z; acc[1][3] += xa.y * wb.w;
        acc[2][0] += xa.z * wb.x; acc[2][1] += xa.z * wb.y; acc[2][2] += xa.z * wb.z; acc[2][3] += xa.z * wb.w;
        acc[3][0] += xa.w * wb.x; acc[3][1] += xa.w * wb.y; acc[3][2] += xa.w * wb.z; acc[3][3] += xa.w * wb.w;
    }

#pragma unroll
    for (int a = 0; a < 4; ++a) {
        int i = i0 + tn + a;
        if (i < N) {
            float4 o = make_float4(acc[a][0], acc[a][1], acc[a][2], acc[a][3]);
            *(float4*)(H + (size_t)i * D + tc) = o;
        }
    }
}

// --- out = b + h * dinv^2  (bias + self-loop message, float4 streaming) ----
__global__ __launch_bounds__(256) void init_out(const float* __restrict__ H,
                                                const float* __restrict__ dinv,
                                                const float* __restrict__ b,
                                                float* __restrict__ out, int N) {
    int idx4 = blockIdx.x * 256 + threadIdx.x;  // float4 index; N*16 total
    if (idx4 >= N * 16) return;
    int i = idx4 >> 4;
    int jc = idx4 & 15;
    float di = dinv[i];
    float s = di * di;
    float4 h4 = ((const float4*)H)[idx4];
    float4 b4 = ((const float4*)b)[jc];
    float4 o;
    o.x = b4.x + h4.x * s;
    o.y = b4.y + h4.y * s;
    o.z = b4.z + h4.z * s;
    o.w = b4.w + h4.w * s;
    ((float4*)out)[idx4] = o;
}

// --- edge scatter: 16 lanes per edge, float4 gather + 4 f32 atomics --------
__global__ __launch_bounds__(256) void edge_scatter(const int* __restrict__ src,
                                                    const int* __restrict__ dst,
                                                    const float* __restrict__ dinv,
                                                    const float* __restrict__ H,
                                                    float* __restrict__ out, int nE) {
    int tid = blockIdx.x * 256 + threadIdx.x;
    int e = tid >> 4;
    if (e >= nE) return;
    int l = tid & 15;
    int s = src[e];
    int d = dst[e];
    float c = dinv[s] * dinv[d];
    float4 v = ((const float4*)H)[s * 16 + l];
    float* o = out + (size_t)d * D + l * 4;
    unsafeAtomicAdd(o + 0, v.x * c);
    unsafeAtomicAdd(o + 1, v.y * c);
    unsafeAtomicAdd(o + 2, v.z * c);
    unsafeAtomicAdd(o + 3, v.w * c);
}

extern "C" void kernel_launch(void* const* d_in, const int* in_sizes, int n_in,
                              void* d_out, int out_size, void* d_ws, size_t ws_size,
                              hipStream_t stream) {
    const float* x  = (const float*)d_in[0];
    const int*   ei = (const int*)d_in[1];   // int64 in reference; harness gives int32
    const float* W1 = (const float*)d_in[2];
    const float* b1 = (const float*)d_in[3];
    const float* W2 = (const float*)d_in[4];
    const float* b2 = (const float*)d_in[5];
    float* out = (float*)d_out;

    const int N  = in_sizes[0] / D;        // 100000
    const int nE = in_sizes[1] / 2;        // 1600000
    const int* src = ei;
    const int* dstv = ei + nE;

    // workspace: dinv (N floats) @ 0, feature buffer (N*64 floats) @ 1MB.
    // d_out doubles as the layer-1 activation buffer -> ws use ~27 MB.
    float* dinv = (float*)d_ws;
    float* bufA = (float*)((char*)d_ws + (1 << 20));

    hipMemsetAsync(dinv, 0, (size_t)N * sizeof(float), stream);

    int gb_e1 = (nE + 255) / 256;
    int gb_n  = (N + 255) / 256;
    int gb_g  = (N + 63) / 64;
    int gb_i  = (N * 16 + 255) / 256;
    int gb_e16 = (int)(((long long)nE * 16 + 255) / 256);

    deg_kernel<<<gb_e1, 256, 0, stream>>>(dstv, dinv, nE);
    dinv_kernel<<<gb_n, 256, 0, stream>>>(dinv, N);

    // ---- layer 1: h1 = x@W1^T in bufA; aggregate into d_out ----
    gemm_xwt<<<gb_g, 256, 0, stream>>>(x, W1, bufA, N);
    init_out<<<gb_i, 256, 0, stream>>>(bufA, dinv, b1, out, N);
    edge_scatter<<<gb_e16, 256, 0, stream>>>(src, dstv, dinv, bufA, out, nE);

    // ---- layer 2: h2 = agg1@W2^T in bufA (agg1 lives in d_out); ----
    // init overwrites d_out from bufA only, then edge atomics on top.
    gemm_xwt<<<gb_g, 256, 0, stream>>>(out, W2, bufA, N);
    init_out<<<gb_i, 256, 0, stream>>>(bufA, dinv, b2, out, N);
    edge_scatter<<<gb_e16, 256, 0, stream>>>(src, dstv, dinv, bufA, out, nE);
}

// Round 2
// 488.849 us; speedup vs baseline: 6.0088x; 6.0088x over previous
//
#include <hip/hip_runtime.h>

// ---------------------------------------------------------------------------
// 2-layer GCN. Round 2: replace 102M-f32-atomic edge scatter (1355us/layer,
// WRITE_SIZE 1.6GB of L2-miss RMW traffic) with a dst-CSR built once:
//   deg -> wave-scan offsets -> fill {src,norm} -> per-node wave gather.
// Aggregation does zero output atomics: one coalesced 256B read per edge,
// one coalesced 256B write per node. CSR amortized over both layers.
// ---------------------------------------------------------------------------

#define D 64

// --- degree count: one int atomic per edge on dst --------------------------
__global__ __launch_bounds__(256) void deg_kernel(const int* __restrict__ dst,
                                                  int* __restrict__ deg, int nE) {
    int e = blockIdx.x * 256 + threadIdx.x;
    if (e < nE) atomicAdd(&deg[dst[e]], 1);
}

// --- dinv = rsqrt(deg + 1)  (self loop adds 1; always > 0) -----------------
__global__ __launch_bounds__(256) void dinv_kernel(const int* __restrict__ deg,
                                                   float* __restrict__ dinv, int N) {
    int i = blockIdx.x * 256 + threadIdx.x;
    if (i < N) dinv[i] = rsqrtf((float)deg[i] + 1.0f);
}

// --- off[i] = region start for node i (order-free alloc via wave scan) -----
// Wave-exclusive scan of deg, lane 63 reserves the wave total from a global
// cursor (1563 atomics total). Writes both off[] and cur[] (fill cursors).
__global__ __launch_bounds__(256) void alloc_offsets(const int* __restrict__ deg,
                                                     int* __restrict__ off,
                                                     int* __restrict__ cur,
                                                     int* __restrict__ cursor, int N) {
    int i = blockIdx.x * 256 + threadIdx.x;
    int lane = threadIdx.x & 63;
    int d = (i < N) ? deg[i] : 0;
    int v = d;
#pragma unroll
    for (int s = 1; s < 64; s <<= 1) {
        int u = __shfl_up(v, s);
        if (lane >= s) v += u;
    }
    int excl = v - d;
    int waveTotal = __shfl(v, 63);
    int base = 0;
    if (lane == 0) base = atomicAdd(cursor, waveTotal);
    base = __shfl(base, 0);
    if (i < N) {
        off[i] = base + excl;
        cur[i] = base + excl;
    }
}

// --- fill CSR: entry = {src, norm} (packed) or src only --------------------
template <bool PACKED>
__global__ __launch_bounds__(256) void fill_csr(const int* __restrict__ src,
                                                const int* __restrict__ dst,
                                                const float* __restrict__ dinv,
                                                int* __restrict__ cur,
                                                void* __restrict__ csr, int nE) {
    int e = blockIdx.x * 256 + threadIdx.x;
    if (e >= nE) return;
    int s = src[e], d = dst[e];
    int pos = atomicAdd(&cur[d], 1);
    if (PACKED) {
        float c = dinv[s] * dinv[d];
        ((int2*)csr)[pos] = make_int2(s, __float_as_int(c));
    } else {
        ((int*)csr)[pos] = s;
    }
}

// --- aggregate: one wave per node, lane = output column --------------------
// Per edge: one broadcast 8B (or 4B) CSR read + one coalesced 256B H read.
// Fuses bias + self-loop message. Single coalesced 256B output write.
template <bool PACKED>
__global__ __launch_bounds__(256) void aggregate(const void* __restrict__ csr,
                                                 const int* __restrict__ off,
                                                 const int* __restrict__ deg,
                                                 const float* __restrict__ dinv,
                                                 const float* __restrict__ H,
                                                 const float* __restrict__ b,
                                                 float* __restrict__ out, int N) {
    int node = blockIdx.x * 4 + (threadIdx.x >> 6);
    if (node >= N) return;
    int lane = threadIdx.x & 63;
    int beg = off[node];
    int end = beg + deg[node];
    float dd = dinv[node];
    float acc = b[lane] + H[(size_t)node * D + lane] * (dd * dd);
    int p = beg;
    if (PACKED) {
        const int2* c2 = (const int2*)csr;
        for (; p + 1 < end; p += 2) {                 // unroll-2 for load ILP
            int2 e0 = c2[p], e1 = c2[p + 1];
            acc += H[(size_t)e0.x * D + lane] * __int_as_float(e0.y);
            acc += H[(size_t)e1.x * D + lane] * __int_as_float(e1.y);
        }
        if (p < end) {
            int2 e0 = c2[p];
            acc += H[(size_t)e0.x * D + lane] * __int_as_float(e0.y);
        }
    } else {
        const int* c1 = (const int*)csr;
        for (; p + 1 < end; p += 2) {
            int s0 = c1[p], s1 = c1[p + 1];
            acc += H[(size_t)s0 * D + lane] * (dinv[s0] * dd);
            acc += H[(size_t)s1 * D + lane] * (dinv[s1] * dd);
        }
        if (p < end) {
            int s0 = c1[p];
            acc += H[(size_t)s0 * D + lane] * (dinv[s0] * dd);
        }
    }
    out[(size_t)node * D + lane] = acc;
}

// --- H = X @ W^T : 64x64 block tile, 4x4 register tile (unchanged) ---------
__global__ __launch_bounds__(256) void gemm_xwt(const float* __restrict__ X,
                                                const float* __restrict__ W,
                                                float* __restrict__ H, int N) {
    __shared__ float xt[64 * 68];
    __shared__ float wt[64 * 68];
    const int t = threadIdx.x;
    const int i0 = blockIdx.x * 64;
#pragma unroll
    for (int r = 0; r < 16; ++r) {
        int idx = r * 256 + t;
        int j = idx >> 6, k = idx & 63;
        wt[k * 68 + j] = W[idx];
    }
#pragma unroll
    for (int r = 0; r < 16; ++r) {
        int idx = r * 256 + t;
        int i = idx >> 6, k = idx & 63;
        float v = 0.0f;
        if (i0 + i < N) v = X[(size_t)(i0 + i) * D + k];
        xt[k * 68 + i] = v;
    }
    __syncthreads();
    const int tn = (t & 15) * 4;
    const int tc = (t >> 4) * 4;
    float acc[4][4] = {};
#pragma unroll 8
    for (int k = 0; k < 64; ++k) {
        const float4 xa = *(const float4*)(xt + k * 68 + tn);
        const float4 wb = *(const float4*)(wt + k * 68 + tc);
        acc[0][0] += xa.x * wb.x; acc[0][1] += xa.x * wb.y; acc[0][2] += xa.x * wb.z; acc[0][3] += xa.x * wb.w;
        acc[1][0] += xa.y * wb.x; acc[1][1] += xa.y * wb.y; acc[1][2] += xa.y * wb.z; acc[1][3] += xa.y * wb.w;
        acc[2][0] += xa.z * wb.x; acc[2][1] += xa.z * wb.y; acc[2][2] += xa.z * wb.z; acc[2][3] += xa.z * wb.w;
        acc[3][0] += xa.w * wb.x; acc[3][1] += xa.w * wb.y; acc[3][2] += xa.w * wb.z; acc[3][3] += xa.w * wb.w;
    }
#pragma unroll
    for (int a = 0; a < 4; ++a) {
        int i = i0 + tn + a;
        if (i < N) {
            float4 o = make_float4(acc[a][0], acc[a][1], acc[a][2], acc[a][3]);
            *(float4*)(H + (size_t)i * D + tc) = o;
        }
    }
}

// --- fallback path (round-1) kernels, used only if ws_size is tight --------
__global__ __launch_bounds__(256) void init_out(const float* __restrict__ H,
                                                const float* __restrict__ dinv,
                                                const float* __restrict__ b,
                                                float* __restrict__ out, int N) {
    int idx4 = blockIdx.x * 256 + threadIdx.x;
    if (idx4 >= N * 16) return;
    int i = idx4 >> 4;
    int jc = idx4 & 15;
    float di = dinv[i];
    float s = di * di;
    float4 h4 = ((const float4*)H)[idx4];
    float4 b4 = ((const float4*)b)[jc];
    ((float4*)out)[idx4] = make_float4(b4.x + h4.x * s, b4.y + h4.y * s,
                                       b4.z + h4.z * s, b4.w + h4.w * s);
}

__global__ __launch_bounds__(256) void edge_scatter(const int* __restrict__ src,
                                                    const int* __restrict__ dst,
                                                    const float* __restrict__ dinv,
                                                    const float* __restrict__ H,
                                                    float* __restrict__ out, int nE) {
    int tid = blockIdx.x * 256 + threadIdx.x;
    int e = tid >> 4;
    if (e >= nE) return;
    int l = tid & 15;
    int s = src[e];
    int d = dst[e];
    float c = dinv[s] * dinv[d];
    float4 v = ((const float4*)H)[s * 16 + l];
    float* o = out + (size_t)d * D + l * 4;
    unsafeAtomicAdd(o + 0, v.x * c);
    unsafeAtomicAdd(o + 1, v.y * c);
    unsafeAtomicAdd(o + 2, v.z * c);
    unsafeAtomicAdd(o + 3, v.w * c);
}

static inline size_t align_up(size_t v, size_t a) { return (v + a - 1) & ~(a - 1); }

extern "C" void kernel_launch(void* const* d_in, const int* in_sizes, int n_in,
                              void* d_out, int out_size, void* d_ws, size_t ws_size,
                              hipStream_t stream) {
    const float* x  = (const float*)d_in[0];
    const int*   ei = (const int*)d_in[1];
    const float* W1 = (const float*)d_in[2];
    const float* b1 = (const float*)d_in[3];
    const float* W2 = (const float*)d_in[4];
    const float* b2 = (const float*)d_in[5];
    float* out = (float*)d_out;

    const int N  = in_sizes[0] / D;   // 100000
    const int nE = in_sizes[1] / 2;   // 1600000
    const int* src = ei;
    const int* dstv = ei + nE;

    // --- workspace layout (bump allocator, 256B aligned) ---
    char* base = (char*)d_ws;
    size_t o = 0;
    int* deg    = (int*)(base + o);  o = align_up(o + (size_t)N * 4, 256);
    int* cursor = (int*)(base + o);  o = align_up(o + 4, 256);
    size_t zero_end = o;             // memset deg..cursor
    float* dinv = (float*)(base + o); o = align_up(o + (size_t)N * 4, 256);
    int* off    = (int*)(base + o);  o = align_up(o + (size_t)N * 4, 256);
    int* cur    = (int*)(base + o);  o = align_up(o + (size_t)N * 4, 256);
    size_t o_csr = o;
    size_t need_packed = o_csr + align_up((size_t)nE * 8, 256) + (size_t)N * D * 4;
    size_t need_int    = o_csr + align_up((size_t)nE * 4, 256) + (size_t)N * D * 4;

    int gb_e = (nE + 255) / 256;
    int gb_n = (N + 255) / 256;
    int gb_g = (N + 63) / 64;

    if (ws_size >= need_int) {
        // ---------------- CSR path ----------------
        bool packed = (ws_size >= need_packed);
        size_t csr_bytes = packed ? (size_t)nE * 8 : (size_t)nE * 4;
        void* csr  = (void*)(base + o_csr);
        float* bufA = (float*)(base + align_up(o_csr + csr_bytes, 256));

        hipMemsetAsync(base, 0, zero_end, stream);
        deg_kernel<<<gb_e, 256, 0, stream>>>(dstv, deg, nE);
        dinv_kernel<<<gb_n, 256, 0, stream>>>(deg, dinv, N);
        alloc_offsets<<<gb_n, 256, 0, stream>>>(deg, off, cur, cursor, N);
        if (packed)
            fill_csr<true><<<gb_e, 256, 0, stream>>>(src, dstv, dinv, cur, csr, nE);
        else
            fill_csr<false><<<gb_e, 256, 0, stream>>>(src, dstv, dinv, cur, csr, nE);

        int gb_a = (N + 3) / 4;
        // layer 1
        gemm_xwt<<<gb_g, 256, 0, stream>>>(x, W1, bufA, N);
        if (packed)
            aggregate<true><<<gb_a, 256, 0, stream>>>(csr, off, deg, dinv, bufA, b1, out, N);
        else
            aggregate<false><<<gb_a, 256, 0, stream>>>(csr, off, deg, dinv, bufA, b1, out, N);
        // layer 2 (agg1 lives in d_out)
        gemm_xwt<<<gb_g, 256, 0, stream>>>(out, W2, bufA, N);
        if (packed)
            aggregate<true><<<gb_a, 256, 0, stream>>>(csr, off, deg, dinv, bufA, b2, out, N);
        else
            aggregate<false><<<gb_a, 256, 0, stream>>>(csr, off, deg, dinv, bufA, b2, out, N);
    } else {
        // ---------------- fallback: round-1 atomic path ----------------
        float* bufA = (float*)(base + o_csr);
        hipMemsetAsync(base, 0, zero_end, stream);
        deg_kernel<<<gb_e, 256, 0, stream>>>(dstv, deg, nE);
        dinv_kernel<<<gb_n, 256, 0, stream>>>(deg, dinv, N);
        int gb_i = (N * 16 + 255) / 256;
        int gb_e16 = (int)(((long long)nE * 16 + 255) / 256);
        gemm_xwt<<<gb_g, 256, 0, stream>>>(x, W1, bufA, N);
        init_out<<<gb_i, 256, 0, stream>>>(bufA, dinv, b1, out, N);
        edge_scatter<<<gb_e16, 256, 0, stream>>>(src, dstv, dinv, bufA, out, nE);
        gemm_xwt<<<gb_g, 256, 0, stream>>>(out, W2, bufA, N);
        init_out<<<gb_i, 256, 0, stream>>>(bufA, dinv, b2, out, N);
        edge_scatter<<<gb_e16, 256, 0, stream>>>(src, dstv, dinv, bufA, out, nE);
    }
}

// Round 3
// 436.760 us; speedup vs baseline: 6.7254x; 1.1193x over previous
//
#include <hip/hip_runtime.h>
#include <hip/hip_fp16.h>

// ---------------------------------------------------------------------------
// 2-layer GCN. Round 3: aggregate was latency-bound (28% HBM, 28% VALU).
//  - H stored fp16: halves gather traffic (256B -> 128B per edge) and GEMM
//    write; 12.8MB H doubles effective L2 coverage. fp32 accumulate.
//  - aggregate unrolled x4: 4 CSR reads then 4 independent gathers in
//    flight per latency round-trip (was 2).
// CSR build (deg -> scan offsets -> fill {src,norm}) unchanged.
// ---------------------------------------------------------------------------

#define D 64

// --- degree count: one int atomic per edge on dst --------------------------
__global__ __launch_bounds__(256) void deg_kernel(const int* __restrict__ dst,
                                                  int* __restrict__ deg, int nE) {
    int e = blockIdx.x * 256 + threadIdx.x;
    if (e < nE) atomicAdd(&deg[dst[e]], 1);
}

// --- dinv = rsqrt(deg + 1) -------------------------------------------------
__global__ __launch_bounds__(256) void dinv_kernel(const int* __restrict__ deg,
                                                   float* __restrict__ dinv, int N) {
    int i = blockIdx.x * 256 + threadIdx.x;
    if (i < N) dinv[i] = rsqrtf((float)deg[i] + 1.0f);
}

// --- region offsets via wave scan + 1 atomic per wave ----------------------
__global__ __launch_bounds__(256) void alloc_offsets(const int* __restrict__ deg,
                                                     int* __restrict__ off,
                                                     int* __restrict__ cur,
                                                     int* __restrict__ cursor, int N) {
    int i = blockIdx.x * 256 + threadIdx.x;
    int lane = threadIdx.x & 63;
    int d = (i < N) ? deg[i] : 0;
    int v = d;
#pragma unroll
    for (int s = 1; s < 64; s <<= 1) {
        int u = __shfl_up(v, s);
        if (lane >= s) v += u;
    }
    int excl = v - d;
    int waveTotal = __shfl(v, 63);
    int base = 0;
    if (lane == 0) base = atomicAdd(cursor, waveTotal);
    base = __shfl(base, 0);
    if (i < N) {
        off[i] = base + excl;
        cur[i] = base + excl;
    }
}

// --- fill CSR: entry = {src, norm} -----------------------------------------
__global__ __launch_bounds__(256) void fill_csr(const int* __restrict__ src,
                                                const int* __restrict__ dst,
                                                const float* __restrict__ dinv,
                                                int* __restrict__ cur,
                                                int2* __restrict__ csr, int nE) {
    int e = blockIdx.x * 256 + threadIdx.x;
    if (e >= nE) return;
    int s = src[e], d = dst[e];
    int pos = atomicAdd(&cur[d], 1);
    float c = dinv[s] * dinv[d];
    csr[pos] = make_int2(s, __float_as_int(c));
}

// --- aggregate: one wave per node, lane = column, fp16 H, unroll-4 ---------
__global__ __launch_bounds__(256) void aggregate(const int2* __restrict__ csr,
                                                 const int* __restrict__ off,
                                                 const int* __restrict__ deg,
                                                 const float* __restrict__ dinv,
                                                 const __half* __restrict__ H,
                                                 const float* __restrict__ b,
                                                 float* __restrict__ out, int N) {
    int node = blockIdx.x * 4 + (threadIdx.x >> 6);
    if (node >= N) return;
    int lane = threadIdx.x & 63;
    int beg = off[node];
    int end = beg + deg[node];
    float dd = dinv[node];
    float acc = b[lane] + __half2float(H[(size_t)node * D + lane]) * (dd * dd);
    int p = beg;
    for (; p + 4 <= end; p += 4) {
        int2 e0 = csr[p], e1 = csr[p + 1], e2 = csr[p + 2], e3 = csr[p + 3];
        float h0 = __half2float(H[(size_t)e0.x * D + lane]);
        float h1 = __half2float(H[(size_t)e1.x * D + lane]);
        float h2 = __half2float(H[(size_t)e2.x * D + lane]);
        float h3 = __half2float(H[(size_t)e3.x * D + lane]);
        acc += h0 * __int_as_float(e0.y);
        acc += h1 * __int_as_float(e1.y);
        acc += h2 * __int_as_float(e2.y);
        acc += h3 * __int_as_float(e3.y);
    }
    for (; p < end; ++p) {
        int2 e0 = csr[p];
        acc += __half2float(H[(size_t)e0.x * D + lane]) * __int_as_float(e0.y);
    }
    out[(size_t)node * D + lane] = acc;
}

// --- H(fp16) = X(fp32) @ W^T : 64x64 block tile, 4x4 register tile ---------
__global__ __launch_bounds__(256) void gemm_xwt_h(const float* __restrict__ X,
                                                  const float* __restrict__ W,
                                                  __half* __restrict__ H, int N) {
    __shared__ float xt[64 * 68];
    __shared__ float wt[64 * 68];
    const int t = threadIdx.x;
    const int i0 = blockIdx.x * 64;
#pragma unroll
    for (int r = 0; r < 16; ++r) {
        int idx = r * 256 + t;
        int j = idx >> 6, k = idx & 63;
        wt[k * 68 + j] = W[idx];
    }
#pragma unroll
    for (int r = 0; r < 16; ++r) {
        int idx = r * 256 + t;
        int i = idx >> 6, k = idx & 63;
        float v = 0.0f;
        if (i0 + i < N) v = X[(size_t)(i0 + i) * D + k];
        xt[k * 68 + i] = v;
    }
    __syncthreads();
    const int tn = (t & 15) * 4;
    const int tc = (t >> 4) * 4;
    float acc[4][4] = {};
#pragma unroll 8
    for (int k = 0; k < 64; ++k) {
        const float4 xa = *(const float4*)(xt + k * 68 + tn);
        const float4 wb = *(const float4*)(wt + k * 68 + tc);
        acc[0][0] += xa.x * wb.x; acc[0][1] += xa.x * wb.y; acc[0][2] += xa.x * wb.z; acc[0][3] += xa.x * wb.w;
        acc[1][0] += xa.y * wb.x; acc[1][1] += xa.y * wb.y; acc[1][2] += xa.y * wb.z; acc[1][3] += xa.y * wb.w;
        acc[2][0] += xa.z * wb.x; acc[2][1] += xa.z * wb.y; acc[2][2] += xa.z * wb.z; acc[2][3] += xa.z * wb.w;
        acc[3][0] += xa.w * wb.x; acc[3][1] += xa.w * wb.y; acc[3][2] += xa.w * wb.z; acc[3][3] += xa.w * wb.w;
    }
#pragma unroll
    for (int a = 0; a < 4; ++a) {
        int i = i0 + tn + a;
        if (i < N) {
            union { __half2 h2[2]; uint2 u2; } pk;
            pk.h2[0].x = __float2half_rn(acc[a][0]);
            pk.h2[0].y = __float2half_rn(acc[a][1]);
            pk.h2[1].x = __float2half_rn(acc[a][2]);
            pk.h2[1].y = __float2half_rn(acc[a][3]);
            *(uint2*)(&H[(size_t)i * D + tc]) = pk.u2;
        }
    }
}

// --- fallback path (round-1 fp32 atomic) kernels ---------------------------
__global__ __launch_bounds__(256) void gemm_xwt(const float* __restrict__ X,
                                                const float* __restrict__ W,
                                                float* __restrict__ H, int N) {
    __shared__ float xt[64 * 68];
    __shared__ float wt[64 * 68];
    const int t = threadIdx.x;
    const int i0 = blockIdx.x * 64;
#pragma unroll
    for (int r = 0; r < 16; ++r) {
        int idx = r * 256 + t;
        int j = idx >> 6, k = idx & 63;
        wt[k * 68 + j] = W[idx];
    }
#pragma unroll
    for (int r = 0; r < 16; ++r) {
        int idx = r * 256 + t;
        int i = idx >> 6, k = idx & 63;
        float v = 0.0f;
        if (i0 + i < N) v = X[(size_t)(i0 + i) * D + k];
        xt[k * 68 + i] = v;
    }
    __syncthreads();
    const int tn = (t & 15) * 4;
    const int tc = (t >> 4) * 4;
    float acc[4][4] = {};
#pragma unroll 8
    for (int k = 0; k < 64; ++k) {
        const float4 xa = *(const float4*)(xt + k * 68 + tn);
        const float4 wb = *(const float4*)(wt + k * 68 + tc);
        acc[0][0] += xa.x * wb.x; acc[0][1] += xa.x * wb.y; acc[0][2] += xa.x * wb.z; acc[0][3] += xa.x * wb.w;
        acc[1][0] += xa.y * wb.x; acc[1][1] += xa.y * wb.y; acc[1][2] += xa.y * wb.z; acc[1][3] += xa.y * wb.w;
        acc[2][0] += xa.z * wb.x; acc[2][1] += xa.z * wb.y; acc[2][2] += xa.z * wb.z; acc[2][3] += xa.z * wb.w;
        acc[3][0] += xa.w * wb.x; acc[3][1] += xa.w * wb.y; acc[3][2] += xa.w * wb.z; acc[3][3] += xa.w * wb.w;
    }
#pragma unroll
    for (int a = 0; a < 4; ++a) {
        int i = i0 + tn + a;
        if (i < N) {
            float4 o = make_float4(acc[a][0], acc[a][1], acc[a][2], acc[a][3]);
            *(float4*)(H + (size_t)i * D + tc) = o;
        }
    }
}

__global__ __launch_bounds__(256) void init_out(const float* __restrict__ H,
                                                const float* __restrict__ dinv,
                                                const float* __restrict__ b,
                                                float* __restrict__ out, int N) {
    int idx4 = blockIdx.x * 256 + threadIdx.x;
    if (idx4 >= N * 16) return;
    int i = idx4 >> 4;
    int jc = idx4 & 15;
    float di = dinv[i];
    float s = di * di;
    float4 h4 = ((const float4*)H)[idx4];
    float4 b4 = ((const float4*)b)[jc];
    ((float4*)out)[idx4] = make_float4(b4.x + h4.x * s, b4.y + h4.y * s,
                                       b4.z + h4.z * s, b4.w + h4.w * s);
}

__global__ __launch_bounds__(256) void edge_scatter(const int* __restrict__ src,
                                                    const int* __restrict__ dst,
                                                    const float* __restrict__ dinv,
                                                    const float* __restrict__ H,
                                                    float* __restrict__ out, int nE) {
    int tid = blockIdx.x * 256 + threadIdx.x;
    int e = tid >> 4;
    if (e >= nE) return;
    int l = tid & 15;
    int s = src[e];
    int d = dst[e];
    float c = dinv[s] * dinv[d];
    float4 v = ((const float4*)H)[s * 16 + l];
    float* o = out + (size_t)d * D + l * 4;
    unsafeAtomicAdd(o + 0, v.x * c);
    unsafeAtomicAdd(o + 1, v.y * c);
    unsafeAtomicAdd(o + 2, v.z * c);
    unsafeAtomicAdd(o + 3, v.w * c);
}

static inline size_t align_up(size_t v, size_t a) { return (v + a - 1) & ~(a - 1); }

extern "C" void kernel_launch(void* const* d_in, const int* in_sizes, int n_in,
                              void* d_out, int out_size, void* d_ws, size_t ws_size,
                              hipStream_t stream) {
    const float* x  = (const float*)d_in[0];
    const int*   ei = (const int*)d_in[1];
    const float* W1 = (const float*)d_in[2];
    const float* b1 = (const float*)d_in[3];
    const float* W2 = (const float*)d_in[4];
    const float* b2 = (const float*)d_in[5];
    float* out = (float*)d_out;

    const int N  = in_sizes[0] / D;   // 100000
    const int nE = in_sizes[1] / 2;   // 1600000
    const int* src = ei;
    const int* dstv = ei + nE;

    // --- workspace layout (bump allocator, 256B aligned) ---
    char* base = (char*)d_ws;
    size_t o = 0;
    int* deg    = (int*)(base + o);  o = align_up(o + (size_t)N * 4, 256);
    int* cursor = (int*)(base + o);  o = align_up(o + 4, 256);
    size_t zero_end = o;             // memset deg..cursor
    float* dinv = (float*)(base + o); o = align_up(o + (size_t)N * 4, 256);
    int* off    = (int*)(base + o);  o = align_up(o + (size_t)N * 4, 256);
    int* cur    = (int*)(base + o);  o = align_up(o + (size_t)N * 4, 256);
    size_t o_csr = o;
    // CSR path: CSR (nE*8) + fp16 H buffer (N*D*2)
    size_t need_csr = o_csr + align_up((size_t)nE * 8, 256) + (size_t)N * D * 2;
    // fallback: fp32 H buffer only
    size_t need_fb  = o_csr + (size_t)N * D * 4;

    int gb_e = (nE + 255) / 256;
    int gb_n = (N + 255) / 256;
    int gb_g = (N + 63) / 64;

    if (ws_size >= need_csr) {
        // ---------------- CSR + fp16-H path ----------------
        int2* csr   = (int2*)(base + o_csr);
        __half* Hh  = (__half*)(base + align_up(o_csr + (size_t)nE * 8, 256));

        hipMemsetAsync(base, 0, zero_end, stream);
        deg_kernel<<<gb_e, 256, 0, stream>>>(dstv, deg, nE);
        dinv_kernel<<<gb_n, 256, 0, stream>>>(deg, dinv, N);
        alloc_offsets<<<gb_n, 256, 0, stream>>>(deg, off, cur, cursor, N);
        fill_csr<<<gb_e, 256, 0, stream>>>(src, dstv, dinv, cur, csr, nE);

        int gb_a = (N + 3) / 4;
        // layer 1
        gemm_xwt_h<<<gb_g, 256, 0, stream>>>(x, W1, Hh, N);
        aggregate<<<gb_a, 256, 0, stream>>>(csr, off, deg, dinv, Hh, b1, out, N);
        // layer 2 (agg1 lives in d_out, fp32)
        gemm_xwt_h<<<gb_g, 256, 0, stream>>>(out, W2, Hh, N);
        aggregate<<<gb_a, 256, 0, stream>>>(csr, off, deg, dinv, Hh, b2, out, N);
    } else if (ws_size >= need_fb) {
        // ---------------- fallback: round-1 atomic path ----------------
        float* bufA = (float*)(base + o_csr);
        hipMemsetAsync(base, 0, zero_end, stream);
        deg_kernel<<<gb_e, 256, 0, stream>>>(dstv, deg, nE);
        dinv_kernel<<<gb_n, 256, 0, stream>>>(deg, dinv, N);
        int gb_i = (N * 16 + 255) / 256;
        int gb_e16 = (int)(((long long)nE * 16 + 255) / 256);
        gemm_xwt<<<gb_g, 256, 0, stream>>>(x, W1, bufA, N);
        init_out<<<gb_i, 256, 0, stream>>>(bufA, dinv, b1, out, N);
        edge_scatter<<<gb_e16, 256, 0, stream>>>(src, dstv, dinv, bufA, out, nE);
        gemm_xwt<<<gb_g, 256, 0, stream>>>(out, W2, bufA, N);
        init_out<<<gb_i, 256, 0, stream>>>(bufA, dinv, b2, out, N);
        edge_scatter<<<gb_e16, 256, 0, stream>>>(src, dstv, dinv, bufA, out, nE);
    }
}